// Round 12
// baseline (382.700 us; speedup 1.0000x reference)
//
#include <hip/hip_runtime.h>
#include <stdint.h>

// MinkFormerBlock on MI355X (gfx950). I/O: f32 in, f32 out (verified R8).
// R25: full-tap stages (one barrier per tap, 125 vs 250) + bnp fused into
// gg<27,2> epilogue. R24: T5 setprio was within noise (+1.5%) -> lockstep
// interpretation confirmed; residual per-stage cost is wait+barrier convoy
// paid 250x. Now: stage = full tap, buffer = A[2 halves 16KB] + B[2 halves
// 16KB] = 64KB, ring of 2 (128KB); 10-op group/wave (A4+B4+idx2); ONE
// vmcnt+lgkm+barrier per tap. K-split retained (wave pair owns 64x64 tile;
// wave computes half-K kk2w -> 16 b128 + 32 MFMA/tap/wave, same totals).
// Channel-phase reverted (full 256B-row gather, FETCH ~330MB) -- proven
// benign by R19<->R20 A/B (FETCH halved, time flat, both directions).
// Ledger FIFO-traced: prologue [G(0)8, idx(1)2, idx(2)2]; steady vmcnt(2)
// (retires G(t) + next idx, leaves newest idx pair in flight); tail
// (2),(0),(0). idx sets E/O alternate statically (pair-unrolled loop),
// each retired by the wait one iter before its consuming stage (asm loads,
// invisible to the compiler waitcnt pass -- R15/R21-proven pattern).
// bnp fusion: gg block owns rows [blk*128,+128) == bnp block exactly;
// accumulate s/q during C-write, shfl_xor over lsub, LDS exchange, write
// psum/psq (removes 2 dispatches + 2x16.7MB re-reads).
//
//   cvt:       xb = bf16(x)            (aliases h_b, dead until ew1)
//   wt:        WT* = bf16(W^T)  [tap][Cout][Cin]
//   gg<1,0>:   a = xb @ Wa1 ; v = xb @ Wv1     (bf16)
//   gg<125,1>: g = gather(a,nbr5)@W5 * v       (bf16, fused gate)
//   gg<27,2>:  t = gather(g,nbr3a)@W31 -> f32, + fused BN partials
//   bnfin -> sc1,sh1 ; ew1: res=bf16->g_b, h=bf16(relu)->h_b
//   gg<27,2>:  t2 = gather(h,nbr3b)@W32 -> f32, + fused BN partials
//   bnfin -> sc2,sh2 ; ew2: d_out = relu(t2*sc+sh + res)  (f32)

#define NPTS 32768
#define C 128
#define EPS 1e-5f

typedef unsigned short u16;
using bfrag = __attribute__((ext_vector_type(8))) short;   // 8 bf16 = 4 VGPRs
using f32x4 = __attribute__((ext_vector_type(4))) float;

__device__ __forceinline__ float b2f(u16 u) {
  union { unsigned int i; float f; } x;
  x.i = ((unsigned int)u) << 16;
  return x.f;
}
__device__ __forceinline__ u16 f2b(float f) {
  union { float f; unsigned int i; } x;
  x.f = f;
  unsigned int r = x.i + 0x7FFFu + ((x.i >> 16) & 1u);   // RNE
  return (u16)(r >> 16);
}

// async global->LDS, 16 B per lane; LDS dest is wave-uniform base + lane*16.
__device__ __forceinline__ void g2l16(const void* g, void* l) {
  __builtin_amdgcn_global_load_lds(
      (const __attribute__((address_space(1))) unsigned int*)g,
      (__attribute__((address_space(3))) unsigned int*)l,
      16, 0, 0);
}

#define GG_W(N)                                                            \
  asm volatile("s_waitcnt vmcnt(" #N ")" ::: "memory");                    \
  __builtin_amdgcn_sched_barrier(0)

// counted vmcnt (own stage-group certified BEFORE barrier) + lgkm drain
// (prev tap's ds_reads, WAR safety) + block barrier + sched fence.
#define GG_WB(N)                                                           \
  asm volatile("s_waitcnt vmcnt(" #N ") lgkmcnt(0)" ::: "memory");         \
  __builtin_amdgcn_s_barrier();                                            \
  __builtin_amdgcn_sched_barrier(0)

// =====================================================================
// Gather-GEMM. Block = 128x128 output, 512 threads, 8 waves. Compute: 4
// tile-pairs -- pair p = (wv&3) owns rows [(p>>1)*64,+64) x cols
// [(p&1)*64,+64); wave computes half-K kk2w = wv>>2 (kk chunks 2*kk2w,
// 2*kk2w+1); acc[4][4] f32x4 partial; 32 MFMA + 16 ds_read_b128 /tap/wave.
// Partials reduced once at epilogue (waves 4-7 -> LDS -> waves 0-3 add).
// LDS ring: buf (t&1) of 2 x 64KB; layout [A: h0 16KB | h1 16KB |
// B: h0 16KB | h1 16KB], rows/cols 128B-stride (zero-conflict, measured).
// Stage group for tap t (issued at iter t-1, by wv -- barrier decouples):
// A 4 g2l16 (rows wv*16+j*8+r8, halves 0/1, chunk cs8^r8 of src+id*256),
// B 4 g2l16 (cols likewise of WT+t*32K), idx 2 asm global_load_dword (for
// tap t+2, retired by iter t+1's vmcnt(2), consumed at iter t+1's stage).
// Per iter t: vmcnt(2)+lgkm(0)+barrier -> stage(t+1) -> loadIdx(t+3) ->
// compute(t). EPI: 0 bf16 out; 1 bf16(acc*vmul); 2 f32 out + BN partials.
// =====================================================================
template <int NTAPS, int EPI>
__global__ __launch_bounds__(512, 1)
void gg_kernel(const u16* __restrict__ src, const u16* __restrict__ WT,
               const int* __restrict__ nbr, u16* __restrict__ outb,
               float* __restrict__ outf, const u16* __restrict__ vmul,
               float* __restrict__ psum, float* __restrict__ psq) {
  __shared__ uint4 lds[8192];          // 128 KB: two 64 KB tap buffers
  char* const base = (char*)lds;
  char* const b0 = base;
  char* const b1 = base + 65536;

  const int tid  = threadIdx.x;
  const int lane = tid & 63;
  const int wv   = tid >> 6;           // 0..7
  const int wq   = wv & 3;             // tile-pair id
  const int wr   = wq >> 1, wc = wq & 1;   // 2x2 grid of 64x64 tiles
  const int kk2w = wv >> 2;            // half-K owned by this wave (0/1)
  const int lsub = lane >> 4, lm = lane & 15;
  const int r8   = lane >> 3;          // DMA: row/col within instr (0..7)
  const int cs8  = lane & 7;           // DMA: chunk slot (0..7, 16 B)
  const int row0 = blockIdx.x * 128;

  f32x4 acc[4][4];
#pragma unroll
  for (int i = 0; i < 4; i++)
#pragma unroll
    for (int j = 0; j < 4; j++) acc[i][j] = (f32x4)(0.0f);

  // ---- idx loads (asm: invisible to waitcnt pass; retired by the counted
  // wait one iteration before their consuming stage)
  auto loadIdx = [&](int (&d)[2], int tp) {
#pragma unroll
    for (int j = 0; j < 2; j++) {
      const int gr = row0 + wv * 16 + j * 8 + r8;
      const int* p = nbr + (size_t)gr * NTAPS + tp;
      asm volatile("global_load_dword %0, %1, off"
                   : "=v"(d[j]) : "v"(p) : "memory");
    }
  };

  // ---- full-tap stage: 8 g2l16/wave (A rows x2 halves, B cols x2 halves)
  auto stageT = [&](char* buf, const int (&id)[2], int tp) {
    const char* wt = (const char*)WT + ((size_t)tp << 15);
#pragma unroll
    for (int j = 0; j < 2; j++) {
      const char* ga = (const char*)src + ((size_t)(unsigned)id[j] << 8)
                     + ((cs8 ^ r8) << 4);
#pragma unroll
      for (int h = 0; h < 2; h++)
        g2l16(ga + (h << 7), buf + h * 16384 + (wv * 16 + j * 8) * 128);
    }
#pragma unroll
    for (int j = 0; j < 2; j++) {
      const int col = wv * 16 + j * 8 + r8;
      const char* gb = wt + ((size_t)col << 8) + ((cs8 ^ r8) << 4);
#pragma unroll
      for (int h = 0; h < 2; h++)
        g2l16(gb + (h << 7), buf + 32768 + h * 16384 + (wv * 16 + j * 8) * 128);
    }
  };

  // ---- one full tap of MFMA (K-split): wave does half h = kk2w, both kx.
  auto computeF = [&](const char* buf) {
    const char* Ah = buf + kk2w * 16384;
    const char* Bh = buf + 32768 + kk2w * 16384;
#pragma unroll
    for (int kx = 0; kx < 2; kx++) {
      bfrag af[4], bg[4];
#pragma unroll
      for (int rt = 0; rt < 4; rt++) {
        const int row = wr * 64 + rt * 16 + lm;
        af[rt] = *(const bfrag*)(Ah + row * 128
                                 + (((kx * 4 + lsub) ^ (row & 7)) << 4));
      }
#pragma unroll
      for (int ct = 0; ct < 4; ct++) {
        const int col = wc * 64 + ct * 16 + lm;
        bg[ct] = *(const bfrag*)(Bh + col * 128
                                 + (((kx * 4 + lsub) ^ (col & 7)) << 4));
      }
      __builtin_amdgcn_s_setprio(1);
#pragma unroll
      for (int rt = 0; rt < 4; rt++)
#pragma unroll
        for (int ct = 0; ct < 4; ct++)
          acc[rt][ct] = __builtin_amdgcn_mfma_f32_16x16x32_bf16(
              af[rt], bg[ct], acc[rt][ct], 0, 0, 0);
      __builtin_amdgcn_s_setprio(0);
    }
  };

  if constexpr (NTAPS == 1) {
    // dense 1x1: identity indices, single full-tap stage, one drain
    int idv[2];
#pragma unroll
    for (int j = 0; j < 2; j++) idv[j] = row0 + wv * 16 + j * 8 + r8;
    stageT(b0, idv, 0);
    GG_WB(0);
    computeF(b0);
  } else {
    int idT[2], idO[2], idE[2];
    // ---- prologue: idx(0) -> drain -> G(0), idx(1)->O, idx(2)->E
    loadIdx(idT, 0);                 // 2 ops
    GG_W(0);                         // retire idx(0)
    stageT(b0, idT, 0);              // 8  -> FIFO: G(0) 8
    loadIdx(idO, 1);                 // +2
    loadIdx(idE, 2);                 // +2 -> 12

    // ---- main: pair-unrolled; iter u: WB(2) retires G(u)+idx(u+1)
    // (leaves idx(u+2) pair), stage tap u+1, load idx(u+3), compute u.
#pragma unroll 1
    for (int t = 0; t < NTAPS - 3; t += 2) {
      GG_WB(2);                      // retire G(t)+idx(t+1)
      stageT(b1, idO, t + 1);        // uses idx(t+1)
      loadIdx(idO, t + 3);
      computeF(b0);
      GG_WB(2);                      // retire G(t+1)+idx(t+2)
      stageT(b0, idE, t + 2);
      loadIdx(idE, t + 4);
      computeF(b1);
    }
    // ---- tail: taps N-3, N-2, N-1 (N odd)
    GG_WB(2);                        // retire G(N-3)+idx(N-2); leave idx(N-1)
    stageT(b1, idO, NTAPS - 2);
    computeF(b0);
    GG_WB(0);                        // retire idx(N-1)+G(N-2)
    stageT(b0, idE, NTAPS - 1);
    computeF(b1);
    GG_WB(0);
    computeF(b0);
  }

  // ---- K-split reduction: waves 4-7 park partials in LDS (64 KB, b0
  // dead after last computeF's ds_reads drain); waves 0-3 add partner's.
  asm volatile("s_waitcnt lgkmcnt(0)" ::: "memory");
  __builtin_amdgcn_s_barrier();
  __builtin_amdgcn_sched_barrier(0);
  if (wv >= 4) {
    char* dst = base + (size_t)(wv - 4) * 16384 + lane * 16;
#pragma unroll
    for (int rt = 0; rt < 4; rt++)
#pragma unroll
      for (int ct = 0; ct < 4; ct++)
        *(f32x4*)(dst + (rt * 4 + ct) * 1024) = acc[rt][ct];
  }
  asm volatile("s_waitcnt lgkmcnt(0)" ::: "memory");
  __builtin_amdgcn_s_barrier();
  __builtin_amdgcn_sched_barrier(0);

  // ---- epilogue write by waves 0-3 (+ fused BN partials for EPI==2).
  // C/D: col = lane&15, row = lsub*4 + reg.
  if (wv < 4) {
    const char* psrc = base + (size_t)wv * 16384 + lane * 16;
    float bs[4] = {0.f, 0.f, 0.f, 0.f}, bq[4] = {0.f, 0.f, 0.f, 0.f};
#pragma unroll
    for (int rt = 0; rt < 4; rt++) {
      const int rowb = row0 + wr * 64 + rt * 16 + lsub * 4;
#pragma unroll
      for (int ct = 0; ct < 4; ct++) {
        const f32x4 part = *(const f32x4*)(psrc + (rt * 4 + ct) * 1024);
        const f32x4 v4 = acc[rt][ct] + part;
        const int c = wc * 64 + ct * 16 + lm;
#pragma unroll
        for (int reg = 0; reg < 4; reg++) {
          const size_t off = (size_t)(rowb + reg) * C + c;
          const float v = v4[reg];
          if (EPI == 0)      outb[off] = f2b(v);
          else if (EPI == 1) outb[off] = f2b(v * b2f(vmul[off]));
          else {
            outf[off] = v;
            bs[ct] += v;
            bq[ct] += v * v;
          }
        }
      }
    }
    if (EPI == 2) {
      // reduce over lsub (4 lanes share column c); park tile-column sums
      float* Sa = (float*)(base + 65536);    // b1 region, dead
#pragma unroll
      for (int ct = 0; ct < 4; ct++) {
        float s = bs[ct], q = bq[ct];
        s += __shfl_xor(s, 16); q += __shfl_xor(q, 16);
        s += __shfl_xor(s, 32); q += __shfl_xor(q, 32);
        if (lsub == 0) {
          Sa[wv * 64 + ct * 16 + lm]       = s;
          Sa[256 + wv * 64 + ct * 16 + lm] = q;
        }
      }
    }
  }
  if (EPI == 2) {
    asm volatile("s_waitcnt lgkmcnt(0)" ::: "memory");
    __builtin_amdgcn_s_barrier();
    __builtin_amdgcn_sched_barrier(0);
    if (tid < 128) {
      const float* Sa = (const float*)(base + 65536);
      const int hi = tid >> 6, lo = tid & 63;
      psum[(size_t)blockIdx.x * 128 + tid] =
          Sa[hi * 64 + lo] + Sa[(hi + 2) * 64 + lo];
      psq[(size_t)blockIdx.x * 128 + tid] =
          Sa[256 + hi * 64 + lo] + Sa[256 + (hi + 2) * 64 + lo];
    }
  }
}

// ---- f32 -> bf16 bulk convert (for x) ------------------------------------
__global__ __launch_bounds__(256)
void cvt_kernel(const float* __restrict__ x, u16* __restrict__ xb) {
  const int i = (blockIdx.x * 256 + threadIdx.x) * 4;
  const float4 v = *(const float4*)(x + i);
  ushort4 o;
  o.x = f2b(v.x); o.y = f2b(v.y); o.z = f2b(v.z); o.w = f2b(v.w);
  *(ushort4*)(xb + i) = o;
}

// ---- weights: f32 [..,Cin,Cout] -> bf16 [..,Cout,Cin] --------------------
__global__ __launch_bounds__(256)
void wt_kernel(const float* __restrict__ W5, const float* __restrict__ W31,
               const float* __restrict__ W32, const float* __restrict__ Wa1,
               const float* __restrict__ Wv1,
               u16* __restrict__ T5, u16* __restrict__ T31, u16* __restrict__ T32,
               u16* __restrict__ Ta1, u16* __restrict__ Tv1) {
  const int b = blockIdx.x;
  const float* w;
  u16* o;
  if (b < 125)       { w = W5  + (size_t)b * 16384;         o = T5  + (size_t)b * 16384; }
  else if (b < 152)  { w = W31 + (size_t)(b - 125) * 16384; o = T31 + (size_t)(b - 125) * 16384; }
  else if (b < 179)  { w = W32 + (size_t)(b - 152) * 16384; o = T32 + (size_t)(b - 152) * 16384; }
  else if (b == 179) { w = Wa1; o = Ta1; }
  else               { w = Wv1; o = Tv1; }
  __shared__ u16 tile[128 * 129];
  for (int i = threadIdx.x; i < C * C; i += 256)
    tile[(i & 127) * 129 + (i >> 7)] = f2b(w[i]);
  __syncthreads();
  for (int i = threadIdx.x; i < C * C; i += 256)
    o[i] = tile[(i >> 7) * 129 + (i & 127)];
}

// ---- bnfin: block c reduces 256 partials (parallel) ----------------------
__global__ __launch_bounds__(256)
void bnfin_kernel(const float* __restrict__ psum, const float* __restrict__ psq,
                  const float* __restrict__ gamma, const float* __restrict__ beta,
                  float* __restrict__ scale, float* __restrict__ shift) {
  const int c = blockIdx.x;
  const int t = threadIdx.x;
  float s = psum[(size_t)t * 128 + c];
  float q = psq[(size_t)t * 128 + c];
#pragma unroll
  for (int o = 32; o > 0; o >>= 1) {
    s += __shfl_down(s, o);
    q += __shfl_down(q, o);
  }
  __shared__ float ls[4], lq[4];
  if ((t & 63) == 0) { ls[t >> 6] = s; lq[t >> 6] = q; }
  __syncthreads();
  if (t == 0) {
    s = ls[0] + ls[1] + ls[2] + ls[3];
    q = lq[0] + lq[1] + lq[2] + lq[3];
    const float mean = s * (1.0f / NPTS);
    const float var  = q * (1.0f / NPTS) - mean * mean;
    const float sc   = rsqrtf(var + EPS) * gamma[c];
    scale[c] = sc;
    shift[c] = beta[c] - mean * sc;
  }
}

// ---- ew1: o = t*sc+sh + x; res=bf16(o); h=bf16(relu o) -------------------
__global__ __launch_bounds__(256)
void ew1_kernel(const float* __restrict__ t, const float* __restrict__ x,
                const float* __restrict__ scale, const float* __restrict__ shift,
                u16* __restrict__ res, u16* __restrict__ h) {
  const int i = blockIdx.x * 256 + threadIdx.x;
  const int c = i & 127;
  const float o = t[i] * scale[c] + shift[c] + x[i];
  res[i] = f2b(o);
  h[i] = f2b(o < 0.f ? 0.f : o);
}

// ---- ew2: y = relu(t2*sc+sh + res) -> f32 d_out --------------------------
__global__ __launch_bounds__(256)
void ew2_kernel(const float* __restrict__ t2, const u16* __restrict__ res,
                const float* __restrict__ scale, const float* __restrict__ shift,
                float* __restrict__ y) {
  const int i = blockIdx.x * 256 + threadIdx.x;
  const int c = i & 127;
  const float o = t2[i] * scale[c] + shift[c] + b2f(res[i]);
  y[i] = o < 0.f ? 0.f : o;
}

// =====================================================================
extern "C" void kernel_launch(void* const* d_in, const int* in_sizes, int n_in,
                              void* d_out, int out_size, void* d_ws, size_t ws_size,
                              hipStream_t stream) {
  (void)in_sizes; (void)n_in; (void)out_size; (void)ws_size;

  const float* x   = (const float*)d_in[0];
  const float* Wa1 = (const float*)d_in[1];
  const float* Wv1 = (const float*)d_in[2];
  const float* W5  = (const float*)d_in[3];
  const float* W31 = (const float*)d_in[4];
  const float* W32 = (const float*)d_in[5];
  const float* g1  = (const float*)d_in[6];
  const float* b1  = (const float*)d_in[7];
  const float* g2  = (const float*)d_in[8];
  const float* b2  = (const float*)d_in[9];
  const int* nbr5  = (const int*)d_in[10];
  const int* nbr3a = (const int*)d_in[11];
  const int* nbr3b = (const int*)d_in[12];

  // ---- workspace (~39.8 MB) ----
  char* w = (char*)d_ws;
  u16* WT5  = (u16*)w; w += 4096000;
  u16* WT31 = (u16*)w; w += 884736;
  u16* WT32 = (u16*)w; w += 884736;
  u16* WTa1 = (u16*)w; w += 32768;
  u16* WTv1 = (u16*)w; w += 32768;
  char* AV  = w;       w += 16777216;          // a | v ; later t/t2 (f32)
  u16*   a_b = (u16*)AV;
  u16*   v_b = (u16*)(AV + 8388608);
  float* tf  = (float*)AV;
  u16* g_b  = (u16*)w; w += 8388608;           // g ; later res (bf16)
  u16* h_b  = (u16*)w; w += 8388608;           // xb first, then h (bf16)
  u16* xb   = h_b;                             // alias: xb dead before ew1
  float* psum = (float*)w; w += 131072;
  float* psq  = (float*)w; w += 131072;
  float* sc1  = (float*)w; w += 512;
  float* sh1  = (float*)w; w += 512;
  float* sc2  = (float*)w; w += 512;
  float* sh2  = (float*)w; w += 512;

  const dim3 B512(512), GG(NPTS / 128), B256(256), GEW(NPTS * C / 256);
  float* yout = (float*)d_out;

  cvt_kernel<<<dim3(NPTS * C / 1024), B256, 0, stream>>>(x, xb);
  wt_kernel<<<dim3(181), B256, 0, stream>>>(W5, W31, W32, Wa1, Wv1,
                                            WT5, WT31, WT32, WTa1, WTv1);

  // a = xb @ Wa1 ; v = xb @ Wv1
  gg_kernel<1, 0><<<GG, B512, 0, stream>>>(xb, WTa1, nullptr, a_b, nullptr, nullptr, nullptr, nullptr);
  gg_kernel<1, 0><<<GG, B512, 0, stream>>>(xb, WTv1, nullptr, v_b, nullptr, nullptr, nullptr, nullptr);

  // g = gather125(a)@W5 * v
  gg_kernel<125, 1><<<GG, B512, 0, stream>>>(a_b, WT5, nbr5, g_b, nullptr, v_b, nullptr, nullptr);

  // t = gather27(g)@W31 -> f32 over AV (a,v dead), BN partials fused
  gg_kernel<27, 2><<<GG, B512, 0, stream>>>(g_b, WT31, nbr3a, nullptr, tf, nullptr, psum, psq);
  bnfin_kernel<<<dim3(128), B256, 0, stream>>>(psum, psq, g1, b1, sc1, sh1);
  ew1_kernel<<<GEW, B256, 0, stream>>>(tf, x, sc1, sh1, g_b, h_b);   // res->g_b, h->h_b (xb dead)

  // t2 = gather27(h)@W32 -> f32 over AV (t dead), BN partials fused
  gg_kernel<27, 2><<<GG, B512, 0, stream>>>(h_b, WT32, nbr3b, nullptr, tf, nullptr, psum, psq);
  bnfin_kernel<<<dim3(128), B256, 0, stream>>>(psum, psq, g2, b2, sc2, sh2);
  ew2_kernel<<<GEW, B256, 0, stream>>>(tf, g_b, sc2, sh2, yout);
}

// Round 13
// 361.105 us; speedup vs baseline: 1.0598x; 1.0598x over previous
//
#include <hip/hip_runtime.h>
#include <stdint.h>

// MinkFormerBlock on MI355X (gfx950). I/O: f32 in, f32 out (verified R8).
// R26: gg reverted to R24 (best: 160.2us gg<125>, 37% MfmaUtil) + R25's one
// verified win kept: BN partials fused into the gg<27,2> epilogue (removes
// bnp x2 dispatches + 2x16.7MB re-reads; correctness harness-verified in
// R25). R25's full-tap-stage merge REGRESSED (-5%): halving barriers gained
// nothing (per-barrier convoy < 100cyc) while reverting channel-phase
// doubled FETCH (170->340MB) and coarsened the pipeline (MfmaUtil 37->35).
// R24 structure recap: K-split wave pairs (64x64 tiles; wave computes
// kk2=wv>>2 only; partials summed once at epilogue via LDS); all-LDS deep
// pipeline (no register-load consumers in loop -> counted vmcnt depth is
// real); 8-wave 128x128 blocks; channel-phase stage order (stage=(tap,half)
// -> gather L2-resident, FETCH ~170MB); 4-deep 32KB ring; 6-op groups
// (A2+B2+idx2); one vmcnt(12)+lgkm(0)+barrier per stage; asm idx retired 3
// stages pre-use; setprio(1) around MFMA cluster (within-noise, kept).
// Ledger FIFO-traced: steady 12; tail 12,10,8,8,4,0. Zero-conflict
// 128B-stride swizzled LDS layout (measured 0).
//
//   cvt:       xb = bf16(x)            (aliases h_b, dead until ew1)
//   wt:        WT* = bf16(W^T)  [tap][Cout][Cin]
//   gg<1,0>:   a = xb @ Wa1 ; v = xb @ Wv1     (bf16)
//   gg<125,1>: g = gather(a,nbr5)@W5 * v       (bf16, fused gate)
//   gg<27,2>:  t = gather(g,nbr3a)@W31 -> f32, + fused BN partials
//   bnfin -> sc1,sh1 ; ew1: res=bf16->g_b, h=bf16(relu)->h_b
//   gg<27,2>:  t2 = gather(h,nbr3b)@W32 -> f32, + fused BN partials
//   bnfin -> sc2,sh2 ; ew2: d_out = relu(t2*sc+sh + res)  (f32)

#define NPTS 32768
#define C 128
#define EPS 1e-5f

typedef unsigned short u16;
using bfrag = __attribute__((ext_vector_type(8))) short;   // 8 bf16 = 4 VGPRs
using f32x4 = __attribute__((ext_vector_type(4))) float;

__device__ __forceinline__ float b2f(u16 u) {
  union { unsigned int i; float f; } x;
  x.i = ((unsigned int)u) << 16;
  return x.f;
}
__device__ __forceinline__ u16 f2b(float f) {
  union { float f; unsigned int i; } x;
  x.f = f;
  unsigned int r = x.i + 0x7FFFu + ((x.i >> 16) & 1u);   // RNE
  return (u16)(r >> 16);
}

// async global->LDS, 16 B per lane; LDS dest is wave-uniform base + lane*16.
__device__ __forceinline__ void g2l16(const void* g, void* l) {
  __builtin_amdgcn_global_load_lds(
      (const __attribute__((address_space(1))) unsigned int*)g,
      (__attribute__((address_space(3))) unsigned int*)l,
      16, 0, 0);
}

#define GG_W(N)                                                            \
  asm volatile("s_waitcnt vmcnt(" #N ")" ::: "memory");                    \
  __builtin_amdgcn_sched_barrier(0)

// counted vmcnt (own stage-group certified BEFORE barrier) + lgkm drain
// (prev stage's ds_reads, WAR safety) + block barrier + sched fence.
#define GG_WB(N)                                                           \
  asm volatile("s_waitcnt vmcnt(" #N ") lgkmcnt(0)" ::: "memory");         \
  __builtin_amdgcn_s_barrier();                                            \
  __builtin_amdgcn_sched_barrier(0)

// =====================================================================
// Gather-GEMM. Block = 128x128 output, 512 threads, 8 waves. Compute: 4
// tile-pairs -- pair p = (wv&3) owns rows [(p>>1)*64,+64) x cols
// [(p&1)*64,+64); wave computes kk2 = wv>>2 only; acc[4][4] f32x4 partial;
// 16 MFMA/stage/wave (setprio(1)-wrapped); 8 ds_read_b128/stage/wave.
// Partials reduced once at epilogue (waves 4-7 -> LDS -> waves 0-3 add).
// Stage s in [0, 2*NTAPS): tap = s<N?s:s-N, half = s<N?0:1 (channel-phase).
// LDS ring: buf[s&3] = A-half [128 rows][128B] + B-half [128 cols][128B].
// Stage group (issued at stage s-3, by wv -- barrier decouples): A 2 g2l16
// (rows wv*16+j*8+r8, chunk cs8^r8 of src+id*256+h*128), B 2 g2l16 (cols
// likewise of WT+tap*32K+h*128), idx 2 asm global_load_dword (for stage
// s+6, consumed s+3). Reads at slot (kk2*4+lsub)^(row&7): zero-conflict.
// EPI: 0 bf16 out; 1 bf16(acc*vmul); 2 f32 out + fused BN partials.
// =====================================================================
template <int NTAPS, int EPI>
__global__ __launch_bounds__(512, 1)
void gg_kernel(const u16* __restrict__ src, const u16* __restrict__ WT,
               const int* __restrict__ nbr, u16* __restrict__ outb,
               float* __restrict__ outf, const u16* __restrict__ vmul,
               float* __restrict__ psum, float* __restrict__ psq) {
  __shared__ uint4 lds[8192];          // 128 KB: four 32 KB stage buffers
  char* const base = (char*)lds;
  char* const bufs[4] = {base, base + 32768, base + 65536, base + 98304};

  const int tid  = threadIdx.x;
  const int lane = tid & 63;
  const int wv   = tid >> 6;           // 0..7
  const int wq   = wv & 3;             // tile-pair id
  const int wr   = wq >> 1, wc = wq & 1;   // 2x2 grid of 64x64 tiles
  const int kk2w = wv >> 2;            // K-chunk owned by this wave (0/1)
  const int lsub = lane >> 4, lm = lane & 15;
  const int r8   = lane >> 3;          // DMA: row/col within instr (0..7)
  const int cs8  = lane & 7;           // DMA: chunk slot (0..7, 16 B)
  const int row0 = blockIdx.x * 128;

  f32x4 acc[4][4];
#pragma unroll
  for (int i = 0; i < 4; i++)
#pragma unroll
    for (int j = 0; j < 4; j++) acc[i][j] = (f32x4)(0.0f);

  // ---- idx loads (asm: invisible to waitcnt pass; retired by the manual
  // waits exactly 3 stages before use)
  auto loadIdx = [&](int (&d)[2], int st) {
    const int tp = st < NTAPS ? st : st - NTAPS;
#pragma unroll
    for (int j = 0; j < 2; j++) {
      const int gr = row0 + wv * 16 + j * 8 + r8;
      const int* p = nbr + (size_t)gr * NTAPS + tp;
      asm volatile("global_load_dword %0, %1, off"
                   : "=v"(d[j]) : "v"(p) : "memory");
    }
  };

  // ---- A half-stage for stage st (2 DMA/wave)
  auto stageA = [&](char* buf, const int (&id)[2], int st) {
    const int h = st < NTAPS ? 0 : 1;
#pragma unroll
    for (int j = 0; j < 2; j++) {
      const char* gp = (const char*)src + ((size_t)(unsigned)id[j] << 8)
                     + (h << 7) + ((cs8 ^ r8) << 4);
      g2l16(gp, buf + (wv * 16 + j * 8) * 128);
    }
  };

  // ---- B half-stage for stage st (2 DMA/wave)
  auto stageB = [&](char* buf, int st) {
    const int tp = st < NTAPS ? st : st - NTAPS;
    const int h = st < NTAPS ? 0 : 1;
    const char* wt = (const char*)WT + ((size_t)tp << 15) + (h << 7);
#pragma unroll
    for (int j = 0; j < 2; j++) {
      const int col = wv * 16 + j * 8 + r8;
      g2l16(wt + ((size_t)col << 8) + ((cs8 ^ r8) << 4),
            buf + 16384 + (wv * 16 + j * 8) * 128);
    }
  };

  // ---- one stage of MFMA (K-split): this wave does only kk2 = kk2w.
  // 64x64 tile: 4 af + 4 bg = 8 ds_read_b128, 16 MFMA (setprio-wrapped).
  auto computeS = [&](const char* buf) {
    bfrag af[4], bg[4];
#pragma unroll
    for (int rt = 0; rt < 4; rt++) {
      const int row = wr * 64 + rt * 16 + lm;
      af[rt] = *(const bfrag*)(buf + row * 128
                               + (((kk2w * 4 + lsub) ^ (row & 7)) << 4));
    }
#pragma unroll
    for (int ct = 0; ct < 4; ct++) {
      const int col = wc * 64 + ct * 16 + lm;
      bg[ct] = *(const bfrag*)(buf + 16384 + col * 128
                               + (((kk2w * 4 + lsub) ^ (col & 7)) << 4));
    }
    __builtin_amdgcn_s_setprio(1);
#pragma unroll
    for (int rt = 0; rt < 4; rt++)
#pragma unroll
      for (int ct = 0; ct < 4; ct++)
        acc[rt][ct] = __builtin_amdgcn_mfma_f32_16x16x32_bf16(
            af[rt], bg[ct], acc[rt][ct], 0, 0, 0);
    __builtin_amdgcn_s_setprio(0);
  };

  if constexpr (NTAPS == 1) {
    // dense 1x1: identity indices, both halves staged, one drain, K-split
    int idv[2];
#pragma unroll
    for (int j = 0; j < 2; j++) idv[j] = row0 + wv * 16 + j * 8 + r8;
    stageA(bufs[0], idv, 0); stageB(bufs[0], 0);   // tap0 h0
    stageA(bufs[1], idv, 1); stageB(bufs[1], 1);   // tap0 h1
    GG_WB(0);
    computeS(bufs[0]);
    computeS(bufs[1]);
  } else {
    constexpr int S = 2 * NTAPS;         // stages; N odd -> S-6 % 4 == 0
    int idr[4][2], ip0[2], ip1[2], ip2[2];
    // ---- prologue: idx(0..2) -> drain -> groups G(-3),G(-2),G(-1)
    loadIdx(ip0, 0); loadIdx(ip1, 1); loadIdx(ip2, 2);   // 6 ops
    GG_W(0);
    stageA(bufs[0], ip0, 0); stageB(bufs[0], 0); loadIdx(idr[1], 3);
    stageA(bufs[1], ip1, 1); stageB(bufs[1], 1); loadIdx(idr[2], 4);
    stageA(bufs[2], ip2, 2); stageB(bufs[2], 2); loadIdx(idr[3], 5);
    // FIFO = 18 = three 6-op groups; steady invariant holds from stage 0.

    // ---- main: stage s consumes idr[(s+1)&3] (idx of stage s+3, loaded at
    // s-3), loads idr[s&3] <- idx(stage s+6). One wait per stage.
#define GG_SUB(p)                                                          \
    GG_WB(12);                                                             \
    stageA(bufs[((p) + 3) & 3], idr[((p) + 1) & 3], s + (p) + 3);          \
    stageB(bufs[((p) + 3) & 3], s + (p) + 3);                              \
    loadIdx(idr[(p) & 3], s + (p) + 6);                                    \
    computeS(bufs[(p) & 3]);

#pragma unroll 1
    for (int s = 0; s < S - 6; s += 4) {
      GG_SUB(0)
      GG_SUB(1)
      GG_SUB(2)
      GG_SUB(3)
    }
#undef GG_SUB

    // ---- tail: stages S-6..S-1 (phases 0,1,2,3,0,1), no idx loads.
    // idx slots: S%4==2 -> idx(S-3)@slot1, idx(S-2)@slot2, idx(S-1)@slot3.
    GG_WB(12);
    stageA(bufs[3], idr[1], S - 3); stageB(bufs[3], S - 3);
    computeS(bufs[0]);                   // stage S-6
    GG_WB(10);
    stageA(bufs[0], idr[2], S - 2); stageB(bufs[0], S - 2);
    computeS(bufs[1]);                   // stage S-5
    GG_WB(8);
    stageA(bufs[1], idr[3], S - 1); stageB(bufs[1], S - 1);
    computeS(bufs[2]);                   // stage S-4
    GG_WB(8);
    computeS(bufs[3]);                   // stage S-3
    GG_WB(4);
    computeS(bufs[0]);                   // stage S-2
    GG_WB(0);
    computeS(bufs[1]);                   // stage S-1
  }

  // ---- K-split reduction: waves 4-7 park partials in LDS (64 KB, ring
  // buffers dead after last computeS); waves 0-3 add partner's partial.
  asm volatile("s_waitcnt lgkmcnt(0)" ::: "memory");
  __builtin_amdgcn_s_barrier();          // all compute ds_reads done
  __builtin_amdgcn_sched_barrier(0);
  if (wv >= 4) {
    char* dst = base + (size_t)(wv - 4) * 16384 + lane * 16;
#pragma unroll
    for (int rt = 0; rt < 4; rt++)
#pragma unroll
      for (int ct = 0; ct < 4; ct++)
        *(f32x4*)(dst + (rt * 4 + ct) * 1024) = acc[rt][ct];
  }
  asm volatile("s_waitcnt lgkmcnt(0)" ::: "memory");
  __builtin_amdgcn_s_barrier();
  __builtin_amdgcn_sched_barrier(0);

  // ---- epilogue write by waves 0-3 (+ fused BN partials for EPI==2).
  // C/D: col = lane&15, row = lsub*4 + reg.
  if (wv < 4) {
    const char* psrc = base + (size_t)wv * 16384 + lane * 16;
    float bs[4] = {0.f, 0.f, 0.f, 0.f}, bq[4] = {0.f, 0.f, 0.f, 0.f};
#pragma unroll
    for (int rt = 0; rt < 4; rt++) {
      const int rowb = row0 + wr * 64 + rt * 16 + lsub * 4;
#pragma unroll
      for (int ct = 0; ct < 4; ct++) {
        const f32x4 part = *(const f32x4*)(psrc + (rt * 4 + ct) * 1024);
        const f32x4 v4 = acc[rt][ct] + part;
        const int c = wc * 64 + ct * 16 + lm;
#pragma unroll
        for (int reg = 0; reg < 4; reg++) {
          const size_t off = (size_t)(rowb + reg) * C + c;
          const float v = v4[reg];
          if (EPI == 0)      outb[off] = f2b(v);
          else if (EPI == 1) outb[off] = f2b(v * b2f(vmul[off]));
          else {
            outf[off] = v;
            bs[ct] += v;
            bq[ct] += v * v;
          }
        }
      }
    }
    if (EPI == 2) {
      // reduce over lsub (4 lanes share column c); park tile-column sums.
      // Sa in bufs[2] region (dead: all LDS reads drained above).
      float* Sa = (float*)(base + 65536);
#pragma unroll
      for (int ct = 0; ct < 4; ct++) {
        float s = bs[ct], q = bq[ct];
        s += __shfl_xor(s, 16); q += __shfl_xor(q, 16);
        s += __shfl_xor(s, 32); q += __shfl_xor(q, 32);
        if (lsub == 0) {
          Sa[wv * 64 + ct * 16 + lm]       = s;
          Sa[256 + wv * 64 + ct * 16 + lm] = q;
        }
      }
    }
  }
  if (EPI == 2) {
    asm volatile("s_waitcnt lgkmcnt(0)" ::: "memory");
    __builtin_amdgcn_s_barrier();
    __builtin_amdgcn_sched_barrier(0);
    if (tid < 128) {
      const float* Sa = (const float*)(base + 65536);
      const int hi = tid >> 6, lo = tid & 63;
      psum[(size_t)blockIdx.x * 128 + tid] =
          Sa[hi * 64 + lo] + Sa[(hi + 2) * 64 + lo];
      psq[(size_t)blockIdx.x * 128 + tid] =
          Sa[256 + hi * 64 + lo] + Sa[256 + (hi + 2) * 64 + lo];
    }
  }
}

// ---- f32 -> bf16 bulk convert (for x) ------------------------------------
__global__ __launch_bounds__(256)
void cvt_kernel(const float* __restrict__ x, u16* __restrict__ xb) {
  const int i = (blockIdx.x * 256 + threadIdx.x) * 4;
  const float4 v = *(const float4*)(x + i);
  ushort4 o;
  o.x = f2b(v.x); o.y = f2b(v.y); o.z = f2b(v.z); o.w = f2b(v.w);
  *(ushort4*)(xb + i) = o;
}

// ---- weights: f32 [..,Cin,Cout] -> bf16 [..,Cout,Cin] --------------------
__global__ __launch_bounds__(256)
void wt_kernel(const float* __restrict__ W5, const float* __restrict__ W31,
               const float* __restrict__ W32, const float* __restrict__ Wa1,
               const float* __restrict__ Wv1,
               u16* __restrict__ T5, u16* __restrict__ T31, u16* __restrict__ T32,
               u16* __restrict__ Ta1, u16* __restrict__ Tv1) {
  const int b = blockIdx.x;
  const float* w;
  u16* o;
  if (b < 125)       { w = W5  + (size_t)b * 16384;         o = T5  + (size_t)b * 16384; }
  else if (b < 152)  { w = W31 + (size_t)(b - 125) * 16384; o = T31 + (size_t)(b - 125) * 16384; }
  else if (b < 179)  { w = W32 + (size_t)(b - 152) * 16384; o = T32 + (size_t)(b - 152) * 16384; }
  else if (b == 179) { w = Wa1; o = Ta1; }
  else               { w = Wv1; o = Tv1; }
  __shared__ u16 tile[128 * 129];
  for (int i = threadIdx.x; i < C * C; i += 256)
    tile[(i & 127) * 129 + (i >> 7)] = f2b(w[i]);
  __syncthreads();
  for (int i = threadIdx.x; i < C * C; i += 256)
    o[i] = tile[(i >> 7) * 129 + (i & 127)];
}

// ---- bnfin: block c reduces 256 partials (parallel) ----------------------
__global__ __launch_bounds__(256)
void bnfin_kernel(const float* __restrict__ psum, const float* __restrict__ psq,
                  const float* __restrict__ gamma, const float* __restrict__ beta,
                  float* __restrict__ scale, float* __restrict__ shift) {
  const int c = blockIdx.x;
  const int t = threadIdx.x;
  float s = psum[(size_t)t * 128 + c];
  float q = psq[(size_t)t * 128 + c];
#pragma unroll
  for (int o = 32; o > 0; o >>= 1) {
    s += __shfl_down(s, o);
    q += __shfl_down(q, o);
  }
  __shared__ float ls[4], lq[4];
  if ((t & 63) == 0) { ls[t >> 6] = s; lq[t >> 6] = q; }
  __syncthreads();
  if (t == 0) {
    s = ls[0] + ls[1] + ls[2] + ls[3];
    q = lq[0] + lq[1] + lq[2] + lq[3];
    const float mean = s * (1.0f / NPTS);
    const float var  = q * (1.0f / NPTS) - mean * mean;
    const float sc   = rsqrtf(var + EPS) * gamma[c];
    scale[c] = sc;
    shift[c] = beta[c] - mean * sc;
  }
}

// ---- ew1: o = t*sc+sh + x; res=bf16(o); h=bf16(relu o) -------------------
__global__ __launch_bounds__(256)
void ew1_kernel(const float* __restrict__ t, const float* __restrict__ x,
                const float* __restrict__ scale, const float* __restrict__ shift,
                u16* __restrict__ res, u16* __restrict__ h) {
  const int i = blockIdx.x * 256 + threadIdx.x;
  const int c = i & 127;
  const float o = t[i] * scale[c] + shift[c] + x[i];
  res[i] = f2b(o);
  h[i] = f2b(o < 0.f ? 0.f : o);
}

// ---- ew2: y = relu(t2*sc+sh + res) -> f32 d_out --------------------------
__global__ __launch_bounds__(256)
void ew2_kernel(const float* __restrict__ t2, const u16* __restrict__ res,
                const float* __restrict__ scale, const float* __restrict__ shift,
                float* __restrict__ y) {
  const int i = blockIdx.x * 256 + threadIdx.x;
  const int c = i & 127;
  const float o = t2[i] * scale[c] + shift[c] + b2f(res[i]);
  y[i] = o < 0.f ? 0.f : o;
}

// =====================================================================
extern "C" void kernel_launch(void* const* d_in, const int* in_sizes, int n_in,
                              void* d_out, int out_size, void* d_ws, size_t ws_size,
                              hipStream_t stream) {
  (void)in_sizes; (void)n_in; (void)out_size; (void)ws_size;

  const float* x   = (const float*)d_in[0];
  const float* Wa1 = (const float*)d_in[1];
  const float* Wv1 = (const float*)d_in[2];
  const float* W5  = (const float*)d_in[3];
  const float* W31 = (const float*)d_in[4];
  const float* W32 = (const float*)d_in[5];
  const float* g1  = (const float*)d_in[6];
  const float* b1  = (const float*)d_in[7];
  const float* g2  = (const float*)d_in[8];
  const float* b2  = (const float*)d_in[9];
  const int* nbr5  = (const int*)d_in[10];
  const int* nbr3a = (const int*)d_in[11];
  const int* nbr3b = (const int*)d_in[12];

  // ---- workspace (~39.8 MB) ----
  char* w = (char*)d_ws;
  u16* WT5  = (u16*)w; w += 4096000;
  u16* WT31 = (u16*)w; w += 884736;
  u16* WT32 = (u16*)w; w += 884736;
  u16* WTa1 = (u16*)w; w += 32768;
  u16* WTv1 = (u16*)w; w += 32768;
  char* AV  = w;       w += 16777216;          // a | v ; later t/t2 (f32)
  u16*   a_b = (u16*)AV;
  u16*   v_b = (u16*)(AV + 8388608);
  float* tf  = (float*)AV;
  u16* g_b  = (u16*)w; w += 8388608;           // g ; later res (bf16)
  u16* h_b  = (u16*)w; w += 8388608;           // xb first, then h (bf16)
  u16* xb   = h_b;                             // alias: xb dead before ew1
  float* psum = (float*)w; w += 131072;
  float* psq  = (float*)w; w += 131072;
  float* sc1  = (float*)w; w += 512;
  float* sh1  = (float*)w; w += 512;
  float* sc2  = (float*)w; w += 512;
  float* sh2  = (float*)w; w += 512;

  const dim3 B512(512), GG(NPTS / 128), B256(256), GEW(NPTS * C / 256);
  float* yout = (float*)d_out;

  cvt_kernel<<<dim3(NPTS * C / 1024), B256, 0, stream>>>(x, xb);
  wt_kernel<<<dim3(181), B256, 0, stream>>>(W5, W31, W32, Wa1, Wv1,
                                            WT5, WT31, WT32, WTa1, WTv1);

  // a = xb @ Wa1 ; v = xb @ Wv1
  gg_kernel<1, 0><<<GG, B512, 0, stream>>>(xb, WTa1, nullptr, a_b, nullptr, nullptr, nullptr, nullptr);
  gg_kernel<1, 0><<<GG, B512, 0, stream>>>(xb, WTv1, nullptr, v_b, nullptr, nullptr, nullptr, nullptr);

  // g = gather125(a)@W5 * v
  gg_kernel<125, 1><<<GG, B512, 0, stream>>>(a_b, WT5, nbr5, g_b, nullptr, v_b, nullptr, nullptr);

  // t = gather27(g)@W31 -> f32 over AV (a,v dead), BN partials fused
  gg_kernel<27, 2><<<GG, B512, 0, stream>>>(g_b, WT31, nbr3a, nullptr, tf, nullptr, psum, psq);
  bnfin_kernel<<<dim3(128), B256, 0, stream>>>(psum, psq, g1, b1, sc1, sh1);
  ew1_kernel<<<GEW, B256, 0, stream>>>(tf, x, sc1, sh1, g_b, h_b);   // res->g_b, h->h_b (xb dead)

  // t2 = gather27(h)@W32 -> f32 over AV (t dead), BN partials fused
  gg_kernel<27, 2><<<GG, B512, 0, stream>>>(h_b, WT32, nbr3b, nullptr, tf, nullptr, psum, psq);
  bnfin_kernel<<<dim3(128), B256, 0, stream>>>(psum, psq, g2, b2, sc2, sh2);
  ew2_kernel<<<GEW, B256, 0, stream>>>(tf, g_b, sc2, sh2, yout);
}

// Round 14
// 360.416 us; speedup vs baseline: 1.0618x; 1.0019x over previous
//
#include <hip/hip_runtime.h>
#include <stdint.h>

// MinkFormerBlock on MI355X (gfx950). I/O: f32 in, f32 out (verified R8).
// R27: R26's gg kernels BYTE-IDENTICAL (plateau verified: 159.5us gg<125>,
// 37% MfmaUtil = structure-class ceiling; R25 bounded per-barrier overhead
// <100cyc; remaining gg levers are high-risk 8-phase restructures). This
// round polishes the ~115us non-gg tail: (1) ew1/ew2 vectorized float4 x4
// elems/thread (were scalar 4B/lane -- Guideline 13; ~100MB traffic), (2)
// wt_kernel 4-way split (181 -> 724 blocks; was latency-bound at 64
// serial elems/thread on 181/256 CUs).
// R26/R24 gg recap: K-split wave pairs (64x64 tiles; wave computes
// kk2=wv>>2; partials summed once at epilogue via LDS); all-LDS deep
// pipeline (no register-load consumers in loop); 8-wave 128x128 blocks;
// channel-phase stage order (gather L2-resident, FETCH ~170MB); 4-deep
// 32KB ring; 6-op groups (A2+B2+idx2); one vmcnt(12)+lgkm(0)+barrier per
// stage; asm idx retired 3 stages pre-use; setprio around MFMA; fused BN
// partials in EPI==2 epilogue. Ledger FIFO-traced: steady 12; tail
// 12,10,8,8,4,0. Zero-conflict 128B-stride swizzled LDS (measured 0).
//
//   cvt:       xb = bf16(x)            (aliases h_b, dead until ew1)
//   wt:        WT* = bf16(W^T)  [tap][Cout][Cin]
//   gg<1,0>:   a = xb @ Wa1 ; v = xb @ Wv1     (bf16)
//   gg<125,1>: g = gather(a,nbr5)@W5 * v       (bf16, fused gate)
//   gg<27,2>:  t = gather(g,nbr3a)@W31 -> f32, + fused BN partials
//   bnfin -> sc1,sh1 ; ew1: res=bf16->g_b, h=bf16(relu)->h_b
//   gg<27,2>:  t2 = gather(h,nbr3b)@W32 -> f32, + fused BN partials
//   bnfin -> sc2,sh2 ; ew2: d_out = relu(t2*sc+sh + res)  (f32)

#define NPTS 32768
#define C 128
#define EPS 1e-5f

typedef unsigned short u16;
using bfrag = __attribute__((ext_vector_type(8))) short;   // 8 bf16 = 4 VGPRs
using f32x4 = __attribute__((ext_vector_type(4))) float;

__device__ __forceinline__ float b2f(u16 u) {
  union { unsigned int i; float f; } x;
  x.i = ((unsigned int)u) << 16;
  return x.f;
}
__device__ __forceinline__ u16 f2b(float f) {
  union { float f; unsigned int i; } x;
  x.f = f;
  unsigned int r = x.i + 0x7FFFu + ((x.i >> 16) & 1u);   // RNE
  return (u16)(r >> 16);
}

// async global->LDS, 16 B per lane; LDS dest is wave-uniform base + lane*16.
__device__ __forceinline__ void g2l16(const void* g, void* l) {
  __builtin_amdgcn_global_load_lds(
      (const __attribute__((address_space(1))) unsigned int*)g,
      (__attribute__((address_space(3))) unsigned int*)l,
      16, 0, 0);
}

#define GG_W(N)                                                            \
  asm volatile("s_waitcnt vmcnt(" #N ")" ::: "memory");                    \
  __builtin_amdgcn_sched_barrier(0)

// counted vmcnt (own stage-group certified BEFORE barrier) + lgkm drain
// (prev stage's ds_reads, WAR safety) + block barrier + sched fence.
#define GG_WB(N)                                                           \
  asm volatile("s_waitcnt vmcnt(" #N ") lgkmcnt(0)" ::: "memory");         \
  __builtin_amdgcn_s_barrier();                                            \
  __builtin_amdgcn_sched_barrier(0)

// =====================================================================
// Gather-GEMM (R26, unchanged). Block = 128x128 output, 512 threads, 8
// waves. Compute: 4 tile-pairs -- pair p = (wv&3) owns rows [(p>>1)*64,+64)
// x cols [(p&1)*64,+64); wave computes kk2 = wv>>2 only; acc[4][4] f32x4
// partial; 16 MFMA/stage/wave (setprio-wrapped); 8 ds_read_b128/stage/wave.
// Partials reduced once at epilogue (waves 4-7 -> LDS -> waves 0-3 add).
// Stage s in [0, 2*NTAPS): tap = s<N?s:s-N, half = s<N?0:1 (channel-phase).
// LDS ring: buf[s&3] = A-half [128 rows][128B] + B-half [128 cols][128B].
// EPI: 0 bf16 out; 1 bf16(acc*vmul); 2 f32 out + fused BN partials.
// =====================================================================
template <int NTAPS, int EPI>
__global__ __launch_bounds__(512, 1)
void gg_kernel(const u16* __restrict__ src, const u16* __restrict__ WT,
               const int* __restrict__ nbr, u16* __restrict__ outb,
               float* __restrict__ outf, const u16* __restrict__ vmul,
               float* __restrict__ psum, float* __restrict__ psq) {
  __shared__ uint4 lds[8192];          // 128 KB: four 32 KB stage buffers
  char* const base = (char*)lds;
  char* const bufs[4] = {base, base + 32768, base + 65536, base + 98304};

  const int tid  = threadIdx.x;
  const int lane = tid & 63;
  const int wv   = tid >> 6;           // 0..7
  const int wq   = wv & 3;             // tile-pair id
  const int wr   = wq >> 1, wc = wq & 1;   // 2x2 grid of 64x64 tiles
  const int kk2w = wv >> 2;            // K-chunk owned by this wave (0/1)
  const int lsub = lane >> 4, lm = lane & 15;
  const int r8   = lane >> 3;          // DMA: row/col within instr (0..7)
  const int cs8  = lane & 7;           // DMA: chunk slot (0..7, 16 B)
  const int row0 = blockIdx.x * 128;

  f32x4 acc[4][4];
#pragma unroll
  for (int i = 0; i < 4; i++)
#pragma unroll
    for (int j = 0; j < 4; j++) acc[i][j] = (f32x4)(0.0f);

  // ---- idx loads (asm: invisible to waitcnt pass; retired by the manual
  // waits exactly 3 stages before use)
  auto loadIdx = [&](int (&d)[2], int st) {
    const int tp = st < NTAPS ? st : st - NTAPS;
#pragma unroll
    for (int j = 0; j < 2; j++) {
      const int gr = row0 + wv * 16 + j * 8 + r8;
      const int* p = nbr + (size_t)gr * NTAPS + tp;
      asm volatile("global_load_dword %0, %1, off"
                   : "=v"(d[j]) : "v"(p) : "memory");
    }
  };

  // ---- A half-stage for stage st (2 DMA/wave)
  auto stageA = [&](char* buf, const int (&id)[2], int st) {
    const int h = st < NTAPS ? 0 : 1;
#pragma unroll
    for (int j = 0; j < 2; j++) {
      const char* gp = (const char*)src + ((size_t)(unsigned)id[j] << 8)
                     + (h << 7) + ((cs8 ^ r8) << 4);
      g2l16(gp, buf + (wv * 16 + j * 8) * 128);
    }
  };

  // ---- B half-stage for stage st (2 DMA/wave)
  auto stageB = [&](char* buf, int st) {
    const int tp = st < NTAPS ? st : st - NTAPS;
    const int h = st < NTAPS ? 0 : 1;
    const char* wt = (const char*)WT + ((size_t)tp << 15) + (h << 7);
#pragma unroll
    for (int j = 0; j < 2; j++) {
      const int col = wv * 16 + j * 8 + r8;
      g2l16(wt + ((size_t)col << 8) + ((cs8 ^ r8) << 4),
            buf + 16384 + (wv * 16 + j * 8) * 128);
    }
  };

  // ---- one stage of MFMA (K-split): this wave does only kk2 = kk2w.
  // 64x64 tile: 4 af + 4 bg = 8 ds_read_b128, 16 MFMA (setprio-wrapped).
  auto computeS = [&](const char* buf) {
    bfrag af[4], bg[4];
#pragma unroll
    for (int rt = 0; rt < 4; rt++) {
      const int row = wr * 64 + rt * 16 + lm;
      af[rt] = *(const bfrag*)(buf + row * 128
                               + (((kk2w * 4 + lsub) ^ (row & 7)) << 4));
    }
#pragma unroll
    for (int ct = 0; ct < 4; ct++) {
      const int col = wc * 64 + ct * 16 + lm;
      bg[ct] = *(const bfrag*)(buf + 16384 + col * 128
                               + (((kk2w * 4 + lsub) ^ (col & 7)) << 4));
    }
    __builtin_amdgcn_s_setprio(1);
#pragma unroll
    for (int rt = 0; rt < 4; rt++)
#pragma unroll
      for (int ct = 0; ct < 4; ct++)
        acc[rt][ct] = __builtin_amdgcn_mfma_f32_16x16x32_bf16(
            af[rt], bg[ct], acc[rt][ct], 0, 0, 0);
    __builtin_amdgcn_s_setprio(0);
  };

  if constexpr (NTAPS == 1) {
    // dense 1x1: identity indices, both halves staged, one drain, K-split
    int idv[2];
#pragma unroll
    for (int j = 0; j < 2; j++) idv[j] = row0 + wv * 16 + j * 8 + r8;
    stageA(bufs[0], idv, 0); stageB(bufs[0], 0);   // tap0 h0
    stageA(bufs[1], idv, 1); stageB(bufs[1], 1);   // tap0 h1
    GG_WB(0);
    computeS(bufs[0]);
    computeS(bufs[1]);
  } else {
    constexpr int S = 2 * NTAPS;         // stages; N odd -> S-6 % 4 == 0
    int idr[4][2], ip0[2], ip1[2], ip2[2];
    // ---- prologue: idx(0..2) -> drain -> groups G(-3),G(-2),G(-1)
    loadIdx(ip0, 0); loadIdx(ip1, 1); loadIdx(ip2, 2);   // 6 ops
    GG_W(0);
    stageA(bufs[0], ip0, 0); stageB(bufs[0], 0); loadIdx(idr[1], 3);
    stageA(bufs[1], ip1, 1); stageB(bufs[1], 1); loadIdx(idr[2], 4);
    stageA(bufs[2], ip2, 2); stageB(bufs[2], 2); loadIdx(idr[3], 5);
    // FIFO = 18 = three 6-op groups; steady invariant holds from stage 0.

    // ---- main: stage s consumes idr[(s+1)&3] (idx of stage s+3, loaded at
    // s-3), loads idr[s&3] <- idx(stage s+6). One wait per stage.
#define GG_SUB(p)                                                          \
    GG_WB(12);                                                             \
    stageA(bufs[((p) + 3) & 3], idr[((p) + 1) & 3], s + (p) + 3);          \
    stageB(bufs[((p) + 3) & 3], s + (p) + 3);                              \
    loadIdx(idr[(p) & 3], s + (p) + 6);                                    \
    computeS(bufs[(p) & 3]);

#pragma unroll 1
    for (int s = 0; s < S - 6; s += 4) {
      GG_SUB(0)
      GG_SUB(1)
      GG_SUB(2)
      GG_SUB(3)
    }
#undef GG_SUB

    // ---- tail: stages S-6..S-1 (phases 0,1,2,3,0,1), no idx loads.
    // idx slots: S%4==2 -> idx(S-3)@slot1, idx(S-2)@slot2, idx(S-1)@slot3.
    GG_WB(12);
    stageA(bufs[3], idr[1], S - 3); stageB(bufs[3], S - 3);
    computeS(bufs[0]);                   // stage S-6
    GG_WB(10);
    stageA(bufs[0], idr[2], S - 2); stageB(bufs[0], S - 2);
    computeS(bufs[1]);                   // stage S-5
    GG_WB(8);
    stageA(bufs[1], idr[3], S - 1); stageB(bufs[1], S - 1);
    computeS(bufs[2]);                   // stage S-4
    GG_WB(8);
    computeS(bufs[3]);                   // stage S-3
    GG_WB(4);
    computeS(bufs[0]);                   // stage S-2
    GG_WB(0);
    computeS(bufs[1]);                   // stage S-1
  }

  // ---- K-split reduction: waves 4-7 park partials in LDS (64 KB, ring
  // buffers dead after last computeS); waves 0-3 add partner's partial.
  asm volatile("s_waitcnt lgkmcnt(0)" ::: "memory");
  __builtin_amdgcn_s_barrier();          // all compute ds_reads done
  __builtin_amdgcn_sched_barrier(0);
  if (wv >= 4) {
    char* dst = base + (size_t)(wv - 4) * 16384 + lane * 16;
#pragma unroll
    for (int rt = 0; rt < 4; rt++)
#pragma unroll
      for (int ct = 0; ct < 4; ct++)
        *(f32x4*)(dst + (rt * 4 + ct) * 1024) = acc[rt][ct];
  }
  asm volatile("s_waitcnt lgkmcnt(0)" ::: "memory");
  __builtin_amdgcn_s_barrier();
  __builtin_amdgcn_sched_barrier(0);

  // ---- epilogue write by waves 0-3 (+ fused BN partials for EPI==2).
  // C/D: col = lane&15, row = lsub*4 + reg.
  if (wv < 4) {
    const char* psrc = base + (size_t)wv * 16384 + lane * 16;
    float bs[4] = {0.f, 0.f, 0.f, 0.f}, bq[4] = {0.f, 0.f, 0.f, 0.f};
#pragma unroll
    for (int rt = 0; rt < 4; rt++) {
      const int rowb = row0 + wr * 64 + rt * 16 + lsub * 4;
#pragma unroll
      for (int ct = 0; ct < 4; ct++) {
        const f32x4 part = *(const f32x4*)(psrc + (rt * 4 + ct) * 1024);
        const f32x4 v4 = acc[rt][ct] + part;
        const int c = wc * 64 + ct * 16 + lm;
#pragma unroll
        for (int reg = 0; reg < 4; reg++) {
          const size_t off = (size_t)(rowb + reg) * C + c;
          const float v = v4[reg];
          if (EPI == 0)      outb[off] = f2b(v);
          else if (EPI == 1) outb[off] = f2b(v * b2f(vmul[off]));
          else {
            outf[off] = v;
            bs[ct] += v;
            bq[ct] += v * v;
          }
        }
      }
    }
    if (EPI == 2) {
      // reduce over lsub (4 lanes share column c); park tile-column sums.
      // Sa in bufs[2] region (dead: all LDS reads drained above).
      float* Sa = (float*)(base + 65536);
#pragma unroll
      for (int ct = 0; ct < 4; ct++) {
        float s = bs[ct], q = bq[ct];
        s += __shfl_xor(s, 16); q += __shfl_xor(q, 16);
        s += __shfl_xor(s, 32); q += __shfl_xor(q, 32);
        if (lsub == 0) {
          Sa[wv * 64 + ct * 16 + lm]       = s;
          Sa[256 + wv * 64 + ct * 16 + lm] = q;
        }
      }
    }
  }
  if (EPI == 2) {
    asm volatile("s_waitcnt lgkmcnt(0)" ::: "memory");
    __builtin_amdgcn_s_barrier();
    __builtin_amdgcn_sched_barrier(0);
    if (tid < 128) {
      const float* Sa = (const float*)(base + 65536);
      const int hi = tid >> 6, lo = tid & 63;
      psum[(size_t)blockIdx.x * 128 + tid] =
          Sa[hi * 64 + lo] + Sa[(hi + 2) * 64 + lo];
      psq[(size_t)blockIdx.x * 128 + tid] =
          Sa[256 + hi * 64 + lo] + Sa[256 + (hi + 2) * 64 + lo];
    }
  }
}

// ---- f32 -> bf16 bulk convert (for x) ------------------------------------
__global__ __launch_bounds__(256)
void cvt_kernel(const float* __restrict__ x, u16* __restrict__ xb) {
  const int i = (blockIdx.x * 256 + threadIdx.x) * 4;
  const float4 v = *(const float4*)(x + i);
  ushort4 o;
  o.x = f2b(v.x); o.y = f2b(v.y); o.z = f2b(v.z); o.w = f2b(v.w);
  *(ushort4*)(xb + i) = o;
}

// ---- weights: f32 [..,Cin,Cout] -> bf16 [..,Cout,Cin] --------------------
// R27: 4-way split (block = matrix b, row-quarter q); 724 blocks (was 181,
// latency-bound at 64 serial elems/thread with 181/256 CUs busy).
__global__ __launch_bounds__(256)
void wt_kernel(const float* __restrict__ W5, const float* __restrict__ W31,
               const float* __restrict__ W32, const float* __restrict__ Wa1,
               const float* __restrict__ Wv1,
               u16* __restrict__ T5, u16* __restrict__ T31, u16* __restrict__ T32,
               u16* __restrict__ Ta1, u16* __restrict__ Tv1) {
  const int b = blockIdx.x >> 2;       // matrix id (0..180)
  const int q = blockIdx.x & 3;        // row-quarter (rows q*32..+32)
  const float* w;
  u16* o;
  if (b < 125)       { w = W5  + (size_t)b * 16384;         o = T5  + (size_t)b * 16384; }
  else if (b < 152)  { w = W31 + (size_t)(b - 125) * 16384; o = T31 + (size_t)(b - 125) * 16384; }
  else if (b < 179)  { w = W32 + (size_t)(b - 152) * 16384; o = T32 + (size_t)(b - 152) * 16384; }
  else if (b == 179) { w = Wa1; o = Ta1; }
  else               { w = Wv1; o = Tv1; }
  __shared__ u16 tile[128 * 33];       // [c][rr], +1 pad
  for (int i = threadIdx.x; i < 32 * 128; i += 256) {
    const int rr = i >> 7;             // 0..31
    const int c  = i & 127;
    tile[c * 33 + rr] = f2b(w[(size_t)(q * 32 + rr) * 128 + c]);
  }
  __syncthreads();
  for (int i = threadIdx.x; i < 32 * 128; i += 256) {
    const int c  = i >> 5;             // 0..127
    const int rr = i & 31;
    o[(size_t)c * 128 + q * 32 + rr] = tile[c * 33 + rr];
  }
}

// ---- bnfin: block c reduces 256 partials (parallel) ----------------------
__global__ __launch_bounds__(256)
void bnfin_kernel(const float* __restrict__ psum, const float* __restrict__ psq,
                  const float* __restrict__ gamma, const float* __restrict__ beta,
                  float* __restrict__ scale, float* __restrict__ shift) {
  const int c = blockIdx.x;
  const int t = threadIdx.x;
  float s = psum[(size_t)t * 128 + c];
  float q = psq[(size_t)t * 128 + c];
#pragma unroll
  for (int o = 32; o > 0; o >>= 1) {
    s += __shfl_down(s, o);
    q += __shfl_down(q, o);
  }
  __shared__ float ls[4], lq[4];
  if ((t & 63) == 0) { ls[t >> 6] = s; lq[t >> 6] = q; }
  __syncthreads();
  if (t == 0) {
    s = ls[0] + ls[1] + ls[2] + ls[3];
    q = lq[0] + lq[1] + lq[2] + lq[3];
    const float mean = s * (1.0f / NPTS);
    const float var  = q * (1.0f / NPTS) - mean * mean;
    const float sc   = rsqrtf(var + EPS) * gamma[c];
    scale[c] = sc;
    shift[c] = beta[c] - mean * sc;
  }
}

// ---- ew1 (vectorized x4): o = t*sc+sh + x; res=bf16(o); h=bf16(relu o) ---
__global__ __launch_bounds__(256)
void ew1_kernel(const float* __restrict__ t, const float* __restrict__ x,
                const float* __restrict__ scale, const float* __restrict__ shift,
                u16* __restrict__ res, u16* __restrict__ h) {
  const int i = (blockIdx.x * 256 + threadIdx.x) * 4;
  const int c = i & 127;               // 4 | 128 -> no row crossing
  const float4 t4 = *(const float4*)(t + i);
  const float4 x4 = *(const float4*)(x + i);
  const float o0 = t4.x * scale[c]     + shift[c]     + x4.x;
  const float o1 = t4.y * scale[c + 1] + shift[c + 1] + x4.y;
  const float o2 = t4.z * scale[c + 2] + shift[c + 2] + x4.z;
  const float o3 = t4.w * scale[c + 3] + shift[c + 3] + x4.w;
  ushort4 r4, h4;
  r4.x = f2b(o0); r4.y = f2b(o1); r4.z = f2b(o2); r4.w = f2b(o3);
  h4.x = f2b(o0 < 0.f ? 0.f : o0);
  h4.y = f2b(o1 < 0.f ? 0.f : o1);
  h4.z = f2b(o2 < 0.f ? 0.f : o2);
  h4.w = f2b(o3 < 0.f ? 0.f : o3);
  *(ushort4*)(res + i) = r4;
  *(ushort4*)(h + i)   = h4;
}

// ---- ew2 (vectorized x4): y = relu(t2*sc+sh + res) -> f32 d_out ----------
__global__ __launch_bounds__(256)
void ew2_kernel(const float* __restrict__ t2, const u16* __restrict__ res,
                const float* __restrict__ scale, const float* __restrict__ shift,
                float* __restrict__ y) {
  const int i = (blockIdx.x * 256 + threadIdx.x) * 4;
  const int c = i & 127;
  const float4 t4 = *(const float4*)(t2 + i);
  const ushort4 r4 = *(const ushort4*)(res + i);
  float4 o;
  o.x = t4.x * scale[c]     + shift[c]     + b2f(r4.x);
  o.y = t4.y * scale[c + 1] + shift[c + 1] + b2f(r4.y);
  o.z = t4.z * scale[c + 2] + shift[c + 2] + b2f(r4.z);
  o.w = t4.w * scale[c + 3] + shift[c + 3] + b2f(r4.w);
  o.x = o.x < 0.f ? 0.f : o.x;
  o.y = o.y < 0.f ? 0.f : o.y;
  o.z = o.z < 0.f ? 0.f : o.z;
  o.w = o.w < 0.f ? 0.f : o.w;
  *(float4*)(y + i) = o;
}

// =====================================================================
extern "C" void kernel_launch(void* const* d_in, const int* in_sizes, int n_in,
                              void* d_out, int out_size, void* d_ws, size_t ws_size,
                              hipStream_t stream) {
  (void)in_sizes; (void)n_in; (void)out_size; (void)ws_size;

  const float* x   = (const float*)d_in[0];
  const float* Wa1 = (const float*)d_in[1];
  const float* Wv1 = (const float*)d_in[2];
  const float* W5  = (const float*)d_in[3];
  const float* W31 = (const float*)d_in[4];
  const float* W32 = (const float*)d_in[5];
  const float* g1  = (const float*)d_in[6];
  const float* b1  = (const float*)d_in[7];
  const float* g2  = (const float*)d_in[8];
  const float* b2  = (const float*)d_in[9];
  const int* nbr5  = (const int*)d_in[10];
  const int* nbr3a = (const int*)d_in[11];
  const int* nbr3b = (const int*)d_in[12];

  // ---- workspace (~39.8 MB) ----
  char* w = (char*)d_ws;
  u16* WT5  = (u16*)w; w += 4096000;
  u16* WT31 = (u16*)w; w += 884736;
  u16* WT32 = (u16*)w; w += 884736;
  u16* WTa1 = (u16*)w; w += 32768;
  u16* WTv1 = (u16*)w; w += 32768;
  char* AV  = w;       w += 16777216;          // a | v ; later t/t2 (f32)
  u16*   a_b = (u16*)AV;
  u16*   v_b = (u16*)(AV + 8388608);
  float* tf  = (float*)AV;
  u16* g_b  = (u16*)w; w += 8388608;           // g ; later res (bf16)
  u16* h_b  = (u16*)w; w += 8388608;           // xb first, then h (bf16)
  u16* xb   = h_b;                             // alias: xb dead before ew1
  float* psum = (float*)w; w += 131072;
  float* psq  = (float*)w; w += 131072;
  float* sc1  = (float*)w; w += 512;
  float* sh1  = (float*)w; w += 512;
  float* sc2  = (float*)w; w += 512;
  float* sh2  = (float*)w; w += 512;

  const dim3 B512(512), GG(NPTS / 128), B256(256), GEW4(NPTS * C / 1024);
  float* yout = (float*)d_out;

  cvt_kernel<<<dim3(NPTS * C / 1024), B256, 0, stream>>>(x, xb);
  wt_kernel<<<dim3(181 * 4), B256, 0, stream>>>(W5, W31, W32, Wa1, Wv1,
                                                WT5, WT31, WT32, WTa1, WTv1);

  // a = xb @ Wa1 ; v = xb @ Wv1
  gg_kernel<1, 0><<<GG, B512, 0, stream>>>(xb, WTa1, nullptr, a_b, nullptr, nullptr, nullptr, nullptr);
  gg_kernel<1, 0><<<GG, B512, 0, stream>>>(xb, WTv1, nullptr, v_b, nullptr, nullptr, nullptr, nullptr);

  // g = gather125(a)@W5 * v
  gg_kernel<125, 1><<<GG, B512, 0, stream>>>(a_b, WT5, nbr5, g_b, nullptr, v_b, nullptr, nullptr);

  // t = gather27(g)@W31 -> f32 over AV (a,v dead), BN partials fused
  gg_kernel<27, 2><<<GG, B512, 0, stream>>>(g_b, WT31, nbr3a, nullptr, tf, nullptr, psum, psq);
  bnfin_kernel<<<dim3(128), B256, 0, stream>>>(psum, psq, g1, b1, sc1, sh1);
  ew1_kernel<<<GEW4, B256, 0, stream>>>(tf, x, sc1, sh1, g_b, h_b);   // res->g_b, h->h_b (xb dead)

  // t2 = gather27(h)@W32 -> f32 over AV (t dead), BN partials fused
  gg_kernel<27, 2><<<GG, B512, 0, stream>>>(h_b, WT32, nbr3b, nullptr, tf, nullptr, psum, psq);
  bnfin_kernel<<<dim3(128), B256, 0, stream>>>(psum, psq, g2, b2, sc2, sh2);
  ew2_kernel<<<GEW4, B256, 0, stream>>>(tf, g_b, sc2, sh2, yout);
}